// Round 1
// baseline (1745.133 us; speedup 1.0000x reference)
//
#include <hip/hip_runtime.h>
#include <math.h>

// GlmDSAMoEGate: T=16384 tokens, H=4096, E=256 experts, 8 groups of 32,
// top-2-per-group group scores, top-4 groups, top-8 experts, sigmoid gate.
//
// Round 1: correctness-first fp32 vector-ALU GEMM fused with in-block top-k.
// No fp32 MFMA on CDNA4 -> VALU-bound, floor ~219us.

constexpr int H  = 4096;
constexpr int E  = 256;
constexpr int BM = 32;    // tokens per block
constexpr int BK = 32;    // K tile
constexpr int NTH = 256;  // threads per block
constexpr int TOPK = 8;
constexpr int NGROUP = 8;
constexpr int GSIZE = 32;          // experts per group
constexpr int TOPK_GROUP = 4;
constexpr float SCALE = 2.5f;

struct Stage {
  float a[BK][BM];   // k-major A tile:  4 KB
  float b[BK][E];    // k-major B tile: 32 KB
};

__global__ __launch_bounds__(NTH, 2)
void moe_gate_kernel(const float* __restrict__ x,     // [T][H]
                     const float* __restrict__ w,     // [E][H]
                     const float* __restrict__ bias,  // [E]
                     float* __restrict__ out_idx,     // [T][8] (as float)
                     float* __restrict__ out_w) {     // [T][8]
  __shared__ union {
    Stage st;                 // 36864 B
    float val[BM][E + 1];     // 32896 B  (s_choice = sigmoid(logit)+bias)
  } sm;
  __shared__ float sbias[E];

  const int tid = threadIdx.x;
  const int tx  = tid & 15;   // expert dim: e = 4*tx + 64*c + i
  const int ty  = tid >> 4;   // token dim: t = 2*ty + r   (ty in 0..15)
  const long t0 = (long)blockIdx.x * BM;

  sbias[tid] = bias[tid];     // NTH == E

  float acc[4][4][2];
  #pragma unroll
  for (int c = 0; c < 4; ++c)
    #pragma unroll
    for (int i = 0; i < 4; ++i) {
      acc[c][i][0] = 0.f; acc[c][i][1] = 0.f;
    }

  for (int k0 = 0; k0 < H; k0 += BK) {
    __syncthreads();
    // ---- stage A: 32 tokens x 32 k  (256 float4, 1 per thread) ----
    {
      const int t = tid >> 3, k4 = tid & 7;
      const float4 v = *(const float4*)(x + (t0 + t) * H + k0 + 4 * k4);
      sm.st.a[4 * k4 + 0][t] = v.x;
      sm.st.a[4 * k4 + 1][t] = v.y;
      sm.st.a[4 * k4 + 2][t] = v.z;
      sm.st.a[4 * k4 + 3][t] = v.w;
    }
    // ---- stage B: 256 experts x 32 k (2048 float4, 8 per thread) ----
    #pragma unroll
    for (int p = 0; p < 8; ++p) {
      const int f = tid + p * NTH;
      const int e = f >> 3, k4 = f & 7;
      const float4 v = *(const float4*)(w + (long)e * H + k0 + 4 * k4);
      sm.st.b[4 * k4 + 0][e] = v.x;
      sm.st.b[4 * k4 + 1][e] = v.y;
      sm.st.b[4 * k4 + 2][e] = v.z;
      sm.st.b[4 * k4 + 3][e] = v.w;
    }
    __syncthreads();
    // ---- compute ----
    #pragma unroll 8
    for (int kk = 0; kk < BK; ++kk) {
      const float2 av = *(const float2*)&sm.st.a[kk][2 * ty];
      #pragma unroll
      for (int c = 0; c < 4; ++c) {
        const float4 bv = *(const float4*)&sm.st.b[kk][4 * tx + 64 * c];
        acc[c][0][0] += bv.x * av.x;  acc[c][0][1] += bv.x * av.y;
        acc[c][1][0] += bv.y * av.x;  acc[c][1][1] += bv.y * av.y;
        acc[c][2][0] += bv.z * av.x;  acc[c][2][1] += bv.z * av.y;
        acc[c][3][0] += bv.w * av.x;  acc[c][3][1] += bv.w * av.y;
      }
    }
  }

  // ---- scores_for_choice into LDS ----
  __syncthreads();   // retire last reads of sm.st before union overwrite
  #pragma unroll
  for (int c = 0; c < 4; ++c)
    #pragma unroll
    for (int i = 0; i < 4; ++i) {
      const int e = 4 * tx + 64 * c + i;
      #pragma unroll
      for (int r = 0; r < 2; ++r) {
        const int t = 2 * ty + r;
        const float s = 1.0f / (1.0f + expf(-acc[c][i][r]));  // sigmoid
        sm.val[t][e] = s + sbias[e];                          // s_choice
      }
    }
  __syncthreads();

  // ---- per-token grouped top-k (1 thread per token, lax.top_k semantics) ----
  if (tid < BM) {
    const int t = tid;
    // group scores = sum of top-2 s_choice per group of 32
    float gs[NGROUP];
    #pragma unroll
    for (int g = 0; g < NGROUP; ++g) {
      float m1 = -1e30f, m2 = -1e30f;
      for (int j = 0; j < GSIZE; ++j) {
        const float v = sm.val[t][g * GSIZE + j];
        if (v > m1) { m2 = m1; m1 = v; }
        else if (v > m2) { m2 = v; }
      }
      gs[g] = m1 + m2;
    }
    // top-4 groups (ties -> lowest index, matching lax.top_k)
    unsigned selmask = 0;
    #pragma unroll
    for (int r = 0; r < TOPK_GROUP; ++r) {
      float best = -1e30f; int bg = 0;
      #pragma unroll
      for (int g = 0; g < NGROUP; ++g) {
        if (((selmask >> g) & 1u) == 0 && gs[g] > best) { best = gs[g]; bg = g; }
      }
      selmask |= 1u << bg;
    }
    // top-8 experts over masked scores (masked-out groups compare as 0.0)
    unsigned long long picked[4] = {0ull, 0ull, 0ull, 0ull};
    int   idx[TOPK];
    float wts[TOPK];
    float wsum = 0.f;
    for (int r = 0; r < TOPK; ++r) {
      float best = -1e30f; int be = 0; bool found = false;
      for (int e = 0; e < E; ++e) {
        if ((picked[e >> 6] >> (e & 63)) & 1ull) continue;
        const float v = ((selmask >> (e >> 5)) & 1u) ? sm.val[t][e] : 0.0f;
        if (!found || v > best) { best = v; be = e; found = true; }
      }
      picked[be >> 6] |= 1ull << (be & 63);
      idx[r] = be;
      const float s = sm.val[t][be] - sbias[be];  // recover raw sigmoid score
      wts[r] = s;
      wsum += s;
    }
    const float inv = SCALE / (wsum + 1e-20f);
    #pragma unroll
    for (int r = 0; r < TOPK; ++r) {
      out_idx[(t0 + t) * TOPK + r] = (float)idx[r];
      out_w  [(t0 + t) * TOPK + r] = wts[r] * inv;
    }
  }
}

extern "C" void kernel_launch(void* const* d_in, const int* in_sizes, int n_in,
                              void* d_out, int out_size, void* d_ws, size_t ws_size,
                              hipStream_t stream) {
  const float* x    = (const float*)d_in[0];  // (4,4096,4096) fp32
  const float* w    = (const float*)d_in[1];  // (256,4096) fp32
  const float* bias = (const float*)d_in[2];  // (256,) fp32

  const int T = in_sizes[0] / H;              // 16384
  float* out_idx = (float*)d_out;             // first T*8: indices (as float)
  float* out_w   = (float*)d_out + (long)T * TOPK;  // next T*8: weights

  moe_gate_kernel<<<dim3(T / BM), dim3(NTH), 0, stream>>>(x, w, bias, out_idx, out_w);
}

// Round 2
// 994.078 us; speedup vs baseline: 1.7555x; 1.7555x over previous
//
#include <hip/hip_runtime.h>
#include <math.h>

// GlmDSAMoEGate: T=16384 tokens, H=4096, E=256 experts, 8 groups of 32,
// top-2-per-group group scores, top-4 groups, top-8 experts, sigmoid gate.
//
// Round 2: fp32 VALU GEMM (no fp32 MFMA on CDNA4; floor = 219us at 157 TF).
//  - padded LDS strides (A:36, B:260) -> bank=(4r+c)%32: staging writes 4-way
//    (was 8-way), compute b128 reads conflict-free, rows stay 16B-aligned.
//  - register tile 4 tokens x 8 experts/thread: 3 ds_read_b128 per 32 FMAs.
//  - register prefetch pipeline: next tile's 9 float4 loads issued before
//    compute phase, so global latency overlaps 4096 cyc of FMAs.

constexpr int H  = 4096;
constexpr int E  = 256;
constexpr int BM = 32;    // tokens per block
constexpr int BK = 32;    // K tile
constexpr int NTH = 256;
constexpr int TOPK = 8;
constexpr int NGROUP = 8;
constexpr int GSIZE = 32;
constexpr int TOPK_GROUP = 4;
constexpr float SCALE = 2.5f;

constexpr int ASTR = 36;   // A tile row stride (floats): bank=(4k+t)%32, 16B-aligned rows
constexpr int BSTR = 260;  // B tile row stride (floats): bank=(4k+e)%32, 16B-aligned rows

struct Stage {
  float a[BK][ASTR];   // k-major A:  4608 B
  float b[BK][BSTR];   // k-major B: 33280 B
};

__global__ __launch_bounds__(NTH, 2)
void moe_gate_kernel(const float* __restrict__ x,     // [T][H]
                     const float* __restrict__ w,     // [E][H]
                     const float* __restrict__ bias,  // [E]
                     float* __restrict__ out_idx,     // [T][8] (as float)
                     float* __restrict__ out_w) {     // [T][8]
  __shared__ __align__(16) union {
    Stage st;                 // 37888 B
    float val[BM][E + 1];     // 32896 B (s_choice = sigmoid(logit)+bias)
  } sm;
  __shared__ float sbias[E];

  const int tid = threadIdx.x;
  const int tx  = tid & 31;   // expert dim: e = 4*tx + 128*j + i
  const int ty  = tid >> 5;   // token dim: t = 4*ty + tt   (ty in 0..7)
  const long t0 = (long)blockIdx.x * BM;

  sbias[tid] = bias[tid];     // NTH == E

  // staging coords: one A float4 + eight B float4 per thread
  const int ta = tid >> 3;    // 0..31: token row (A) / expert base (B)
  const int ka = tid & 7;     // k-quad
  const float* xp = x + (t0 + ta) * H + 4 * ka;
  const float* wp = w + (long)ta * H + 4 * ka;

  float4 pa = *(const float4*)xp;
  float4 pb[8];
  #pragma unroll
  for (int p = 0; p < 8; ++p) pb[p] = *(const float4*)(wp + (long)32 * p * H);

  float acc[2][4][4];  // [j: expert half][i: expert elem][t: token]
  #pragma unroll
  for (int j = 0; j < 2; ++j)
    #pragma unroll
    for (int i = 0; i < 4; ++i)
      #pragma unroll
      for (int t = 0; t < 4; ++t) acc[j][i][t] = 0.f;

  for (int k0 = 0; k0 < H; k0 += BK) {
    __syncthreads();   // previous tile's reads retired
    // ---- store prefetched tile to LDS (transposed to k-major) ----
    sm.st.a[4 * ka + 0][ta] = pa.x;
    sm.st.a[4 * ka + 1][ta] = pa.y;
    sm.st.a[4 * ka + 2][ta] = pa.z;
    sm.st.a[4 * ka + 3][ta] = pa.w;
    #pragma unroll
    for (int p = 0; p < 8; ++p) {
      const int e = ta + 32 * p;
      sm.st.b[4 * ka + 0][e] = pb[p].x;
      sm.st.b[4 * ka + 1][e] = pb[p].y;
      sm.st.b[4 * ka + 2][e] = pb[p].z;
      sm.st.b[4 * ka + 3][e] = pb[p].w;
    }
    // ---- prefetch next tile into registers (overlaps compute below) ----
    if (k0 + BK < H) {
      xp += BK; wp += BK;
      pa = *(const float4*)xp;
      #pragma unroll
      for (int p = 0; p < 8; ++p) pb[p] = *(const float4*)(wp + (long)32 * p * H);
    }
    __syncthreads();   // tile visible
    // ---- compute: per kk, 3 ds_read_b128 -> 32 FMAs ----
    #pragma unroll 8
    for (int kk = 0; kk < BK; ++kk) {
      const float4 av = *(const float4*)&sm.st.a[kk][4 * ty];          // 4 tokens
      const float4 b0 = *(const float4*)&sm.st.b[kk][4 * tx];          // experts 4tx..+3
      const float4 b1 = *(const float4*)&sm.st.b[kk][4 * tx + 128];    // experts 128+4tx..+3
      const float avv[4] = {av.x, av.y, av.z, av.w};
      const float bv[2][4] = {{b0.x, b0.y, b0.z, b0.w}, {b1.x, b1.y, b1.z, b1.w}};
      #pragma unroll
      for (int j = 0; j < 2; ++j)
        #pragma unroll
        for (int i = 0; i < 4; ++i)
          #pragma unroll
          for (int t = 0; t < 4; ++t)
            acc[j][i][t] += bv[j][i] * avv[t];
    }
  }

  // ---- scores_for_choice into LDS ----
  __syncthreads();   // retire last reads of sm.st before union overwrite
  #pragma unroll
  for (int j = 0; j < 2; ++j)
    #pragma unroll
    for (int i = 0; i < 4; ++i) {
      const int e = 4 * tx + 128 * j + i;
      const float be = sbias[e];
      #pragma unroll
      for (int t = 0; t < 4; ++t) {
        const float s = 1.0f / (1.0f + expf(-acc[j][i][t]));  // sigmoid
        sm.val[4 * ty + t][e] = s + be;                       // s_choice
      }
    }
  __syncthreads();

  // ---- per-token grouped top-k (1 thread per token, lax.top_k semantics) ----
  if (tid < BM) {
    const int t = tid;
    // group scores = sum of top-2 s_choice per group of 32
    float gs[NGROUP];
    #pragma unroll
    for (int g = 0; g < NGROUP; ++g) {
      float m1 = -1e30f, m2 = -1e30f;
      for (int jj = 0; jj < GSIZE; ++jj) {
        const float v = sm.val[t][g * GSIZE + jj];
        if (v > m1) { m2 = m1; m1 = v; }
        else if (v > m2) { m2 = v; }
      }
      gs[g] = m1 + m2;
    }
    // top-4 groups (ties -> lowest index, matching lax.top_k)
    unsigned selmask = 0;
    #pragma unroll
    for (int r = 0; r < TOPK_GROUP; ++r) {
      float best = -1e30f; int bg = 0;
      #pragma unroll
      for (int g = 0; g < NGROUP; ++g) {
        if (((selmask >> g) & 1u) == 0 && gs[g] > best) { best = gs[g]; bg = g; }
      }
      selmask |= 1u << bg;
    }
    // top-8 experts over masked scores (masked-out groups compare as 0.0)
    unsigned long long picked[4] = {0ull, 0ull, 0ull, 0ull};
    int   idx[TOPK];
    float wts[TOPK];
    float wsum = 0.f;
    for (int r = 0; r < TOPK; ++r) {
      float best = -1e30f; int be = 0; bool found = false;
      for (int e = 0; e < E; ++e) {
        if ((picked[e >> 6] >> (e & 63)) & 1ull) continue;
        const float v = ((selmask >> (e >> 5)) & 1u) ? sm.val[t][e] : 0.0f;
        if (!found || v > best) { best = v; be = e; found = true; }
      }
      picked[be >> 6] |= 1ull << (be & 63);
      idx[r] = be;
      const float s = sm.val[t][be] - sbias[be];  // recover raw sigmoid score
      wts[r] = s;
      wsum += s;
    }
    const float inv = SCALE / (wsum + 1e-20f);
    #pragma unroll
    for (int r = 0; r < TOPK; ++r) {
      out_idx[(t0 + t) * TOPK + r] = (float)idx[r];
      out_w  [(t0 + t) * TOPK + r] = wts[r] * inv;
    }
  }
}

extern "C" void kernel_launch(void* const* d_in, const int* in_sizes, int n_in,
                              void* d_out, int out_size, void* d_ws, size_t ws_size,
                              hipStream_t stream) {
  const float* x    = (const float*)d_in[0];  // (4,4096,4096) fp32
  const float* w    = (const float*)d_in[1];  // (256,4096) fp32
  const float* bias = (const float*)d_in[2];  // (256,) fp32

  const int T = in_sizes[0] / H;              // 16384
  float* out_idx = (float*)d_out;             // first T*8: indices (as float)
  float* out_w   = (float*)d_out + (long)T * TOPK;  // next T*8: weights

  moe_gate_kernel<<<dim3(T / BM), dim3(NTH), 0, stream>>>(x, w, bias, out_idx, out_w);
}

// Round 3
// 958.444 us; speedup vs baseline: 1.8208x; 1.0372x over previous
//
#include <hip/hip_runtime.h>
#include <math.h>

// GlmDSAMoEGate: T=16384 tokens, H=4096, E=256 experts, 8 groups of 32,
// top-2-per-group group scores, top-4 groups, top-8 experts, sigmoid gate.
//
// Round 3: fp32 VALU GEMM (no fp32 MFMA on CDNA4; VALU floor = 219us).
//  - W pre-transposed to Wt[H][E] (kernel 0, ~3us) so the B tile's LDS layout
//    [kk][e] (1KB rows) matches global order -> staged with async
//    global_load_lds width=16: no staging VALU, no conflicts, no VGPR trip.
//  - B reads [kk][4tx]: 32 distinct 16B -> 4cyc optimal. A reads [kk][4ty]:
//    2 distinct addrs/wave -> broadcast ~1cyc. LDS pipe ~10cyc/kk/wave vs
//    VALU 128cyc/SIMD/kk -> VALU-bound (R2 was LDS-bound at 288cyc/CU/kk).
//  - B double-buffered; DMA for tile k+1 issued at top of compute(k), so the
//    vmcnt(0) drain at the next barrier comes ~2000cyc later (hidden).

constexpr int H  = 4096;
constexpr int E  = 256;
constexpr int BM = 32;    // tokens per block
constexpr int BK = 32;    // K tile
constexpr int NTH = 256;
constexpr int TOPK = 8;
constexpr int NGROUP = 8;
constexpr int GSIZE = 32;
constexpr int TOPK_GROUP = 4;
constexpr float SCALE = 2.5f;
constexpr int ASTR = 36;  // A tile row stride: bank=(4kk+4ty+d)%32, b128-aligned

// ---------------- kernel 0: W[E][H] -> Wt[H][E] ----------------
__global__ __launch_bounds__(256)
void transpose_w_kernel(const float* __restrict__ w, float* __restrict__ wt) {
  __shared__ float tile[32][33];
  const int tx = threadIdx.x & 31, ty = threadIdx.x >> 5;  // ty 0..7
  const int k0 = blockIdx.x * 32, e0 = blockIdx.y * 32;
  #pragma unroll
  for (int i = 0; i < 32; i += 8)
    tile[ty + i][tx] = w[(long)(e0 + ty + i) * H + k0 + tx];
  __syncthreads();
  #pragma unroll
  for (int i = 0; i < 32; i += 8)
    wt[(long)(k0 + ty + i) * E + e0 + tx] = tile[tx][ty + i];
}

// ---------------- kernel 1: fused gate ----------------
struct SmemT {
  float a[BK][ASTR];     //  4608 B, k-major A (software-transposed staging)
  float b[2][BK][E];     // 65536 B, double-buffered B, rows = global order
};

__global__ __launch_bounds__(NTH, 2)
void moe_gate_kernel(const float* __restrict__ x,     // [T][H]
                     const float* __restrict__ wt,    // [H][E] (transposed)
                     const float* __restrict__ bias,  // [E]
                     float* __restrict__ out_idx,     // [T][8] (as float)
                     float* __restrict__ out_w) {     // [T][8]
  __shared__ __align__(16) union {
    SmemT st;                 // 70144 B
    float val[BM][E + 1];     // 32896 B
  } sm;
  __shared__ float sbias[E];

  const int tid  = threadIdx.x;
  const int lane = tid & 63;
  const int wave = tid >> 6;        // 0..3
  const int tx   = tid & 31;        // experts: e = 4*tx + 128*j + i
  const int ty   = tid >> 5;        // tokens:  t = 4*ty + r   (ty 0..7)
  const long t0  = (long)blockIdx.x * BM;

  sbias[tid] = bias[tid];           // NTH == E

  // A staging coords: 1 float4 per thread, software transpose to k-major
  const int ta = tid >> 3;          // 0..31 token
  const int ka = tid & 7;           // k-quad
  const float* xp = x + (t0 + ta) * H + 4 * ka;

  // async B staging: wave w stages rows w*8+p (each row = 256 floats = 1KB =
  // exactly one wave-instr of 64 lanes x 16B). LDS dst is wave-uniform.
  auto stage_b = [&](int k0, int buf) {
    #pragma unroll
    for (int p = 0; p < 8; ++p) {
      const int row = wave * 8 + p;
      __builtin_amdgcn_global_load_lds(
          (const __attribute__((address_space(1))) float*)(wt + (long)(k0 + row) * E + lane * 4),
          (__attribute__((address_space(3))) float*)&sm.st.b[buf][row][0],
          16, 0, 0);
    }
  };

  float acc[2][4][4];  // [j: expert half][i: expert elem][r: token]
  #pragma unroll
  for (int j = 0; j < 2; ++j)
    #pragma unroll
    for (int i = 0; i < 4; ++i)
      #pragma unroll
      for (int r = 0; r < 4; ++r) acc[j][i][r] = 0.f;

  // prologue: tile 0 in flight
  stage_b(0, 0);
  float4 pa = *(const float4*)xp;

  constexpr int NT = H / BK;  // 128
  for (int t = 0; t < NT; ++t) {
    const int buf = t & 1;
    __syncthreads();   // (1) prev tile's reads done; drains DMA(t) + pa(t)
                       //     (both had a full compute phase in flight)
    sm.st.a[4 * ka + 0][ta] = pa.x;
    sm.st.a[4 * ka + 1][ta] = pa.y;
    sm.st.a[4 * ka + 2][ta] = pa.z;
    sm.st.a[4 * ka + 3][ta] = pa.w;
    __syncthreads();   // (2) staging visible; only lgkm(A writes) in flight -> cheap
    if (t + 1 < NT) {  // prefetch tile t+1 during compute(t)
      stage_b((t + 1) * BK, buf ^ 1);
      xp += BK;
      pa = *(const float4*)xp;
    }
    #pragma unroll 8
    for (int kk = 0; kk < BK; ++kk) {
      const float4 av = *(const float4*)&sm.st.a[kk][4 * ty];             // 4 tokens (broadcast)
      const float4 b0 = *(const float4*)&sm.st.b[buf][kk][4 * tx];        // experts 4tx..+3
      const float4 b1 = *(const float4*)&sm.st.b[buf][kk][4 * tx + 128];  // experts 128+4tx..+3
      const float avv[4] = {av.x, av.y, av.z, av.w};
      const float bv[2][4] = {{b0.x, b0.y, b0.z, b0.w}, {b1.x, b1.y, b1.z, b1.w}};
      #pragma unroll
      for (int j = 0; j < 2; ++j)
        #pragma unroll
        for (int i = 0; i < 4; ++i)
          #pragma unroll
          for (int r = 0; r < 4; ++r)
            acc[j][i][r] += bv[j][i] * avv[r];
    }
  }

  // ---- scores_for_choice into LDS ----
  __syncthreads();   // retire last reads of sm.st before union overwrite
  #pragma unroll
  for (int j = 0; j < 2; ++j)
    #pragma unroll
    for (int i = 0; i < 4; ++i) {
      const int e = 4 * tx + 128 * j + i;
      const float be = sbias[e];
      #pragma unroll
      for (int r = 0; r < 4; ++r) {
        const float s = 1.0f / (1.0f + expf(-acc[j][i][r]));  // sigmoid
        sm.val[4 * ty + r][e] = s + be;                       // s_choice
      }
    }
  __syncthreads();

  // ---- per-token grouped top-k (1 thread per token, lax.top_k semantics) ----
  if (tid < BM) {
    const int t = tid;
    float gs[NGROUP];
    #pragma unroll
    for (int g = 0; g < NGROUP; ++g) {
      float m1 = -1e30f, m2 = -1e30f;
      for (int jj = 0; jj < GSIZE; ++jj) {
        const float v = sm.val[t][g * GSIZE + jj];
        if (v > m1) { m2 = m1; m1 = v; }
        else if (v > m2) { m2 = v; }
      }
      gs[g] = m1 + m2;
    }
    unsigned selmask = 0;
    #pragma unroll
    for (int r = 0; r < TOPK_GROUP; ++r) {
      float best = -1e30f; int bg = 0;
      #pragma unroll
      for (int g = 0; g < NGROUP; ++g) {
        if (((selmask >> g) & 1u) == 0 && gs[g] > best) { best = gs[g]; bg = g; }
      }
      selmask |= 1u << bg;
    }
    unsigned long long picked[4] = {0ull, 0ull, 0ull, 0ull};
    int   idx[TOPK];
    float wts[TOPK];
    float wsum = 0.f;
    for (int r = 0; r < TOPK; ++r) {
      float best = -1e30f; int be = 0; bool found = false;
      for (int e = 0; e < E; ++e) {
        if ((picked[e >> 6] >> (e & 63)) & 1ull) continue;
        const float v = ((selmask >> (e >> 5)) & 1u) ? sm.val[t][e] : 0.0f;
        if (!found || v > best) { best = v; be = e; found = true; }
      }
      picked[be >> 6] |= 1ull << (be & 63);
      idx[r] = be;
      const float s = sm.val[t][be] - sbias[be];
      wts[r] = s;
      wsum += s;
    }
    const float inv = SCALE / (wsum + 1e-20f);
    #pragma unroll
    for (int r = 0; r < TOPK; ++r) {
      out_idx[(t0 + t) * TOPK + r] = (float)idx[r];
      out_w  [(t0 + t) * TOPK + r] = wts[r] * inv;
    }
  }
}

extern "C" void kernel_launch(void* const* d_in, const int* in_sizes, int n_in,
                              void* d_out, int out_size, void* d_ws, size_t ws_size,
                              hipStream_t stream) {
  const float* x    = (const float*)d_in[0];  // (4,4096,4096) fp32
  const float* w    = (const float*)d_in[1];  // (256,4096) fp32
  const float* bias = (const float*)d_in[2];  // (256,) fp32

  const int T = in_sizes[0] / H;              // 16384
  float* wt = (float*)d_ws;                   // Wt[H][E], 4 MB scratch
  float* out_idx = (float*)d_out;
  float* out_w   = (float*)d_out + (long)T * TOPK;

  transpose_w_kernel<<<dim3(H / 32, E / 32), dim3(256), 0, stream>>>(w, wt);
  moe_gate_kernel<<<dim3(T / BM), dim3(NTH), 0, stream>>>(x, wt, bias, out_idx, out_w);
}